// Round 4
// baseline (647.064 us; speedup 1.0000x reference)
//
#include <hip/hip_runtime.h>
#include <math.h>

#define SIGMA_F 32.0f
#define BB 8
#define CC 31
#define HH 512
#define WW 512
#define PLANE (HH * WW)

#define WIN_R 129
#define WIN_C 132                 // padded stride (mult of 4)
#define LDS_N (WIN_R * WIN_C)     // 17028
#define NF4   (WIN_R * 33)        // 4257 float4 per window

// ---- compile-time Gaussian weights: W[i] = exp(-i^2 / 2048) ----
constexpr double cexp_neg(double t) {
    double u = -t / 16.0;
    double s = 1.0, term = 1.0;
    for (int k = 1; k < 14; ++k) { term *= u / (double)k; s += term; }
    s = s * s; s = s * s; s = s * s; s = s * s;
    return s;
}
constexpr float gwf(int i) { return (float)cexp_neg((double)(i * i) / 2048.0); }

__device__ constexpr float W[64] = {
    gwf(0),  gwf(1),  gwf(2),  gwf(3),  gwf(4),  gwf(5),  gwf(6),  gwf(7),
    gwf(8),  gwf(9),  gwf(10), gwf(11), gwf(12), gwf(13), gwf(14), gwf(15),
    gwf(16), gwf(17), gwf(18), gwf(19), gwf(20), gwf(21), gwf(22), gwf(23),
    gwf(24), gwf(25), gwf(26), gwf(27), gwf(28), gwf(29), gwf(30), gwf(31),
    gwf(32), gwf(33), gwf(34), gwf(35), gwf(36), gwf(37), gwf(38), gwf(39),
    gwf(40), gwf(41), gwf(42), gwf(43), gwf(44), gwf(45), gwf(46), gwf(47),
    gwf(48), gwf(49), gwf(50), gwf(51), gwf(52), gwf(53), gwf(54), gwf(55),
    gwf(56), gwf(57), gwf(58), gwf(59), gwf(60), gwf(61), gwf(62), 0.0f
};

__global__ __launch_bounds__(256, 2) void blur_fused_kernel(const float* __restrict__ dxn,
                                                            const float* __restrict__ dyn,
                                                            float* __restrict__ blur,
                                                            float* __restrict__ partials) {
    __shared__ __align__(16) float vt[16 * 580];
    __shared__ float smax[4];
    int t = threadIdx.x;
    int blk = blockIdx.x;
    int plane = blk >> 5;
    int band = blk & 31;
    int y0 = band << 4;
    const float* src = (plane < BB) ? dxn + (size_t)plane * PLANE
                                    : dyn + (size_t)(plane - BB) * PLANE;

    for (int c = t; c < 574; c += 256) {
        int L = c - 31;
        int scol = (L < 0) ? -L : ((L > HH - 1) ? 2 * HH - 2 - L : L);
        float acc[16];
        #pragma unroll
        for (int j = 0; j < 16; ++j) acc[j] = 0.0f;
        #pragma unroll
        for (int ro = 0; ro < 78; ++ro) {
            int rr = y0 - 31 + ro;
            int r = (rr < 0) ? -rr : ((rr > HH - 1) ? 2 * HH - 2 - rr : rr);
            float v = src[r * WW + scol];
            #pragma unroll
            for (int j = 0; j < 16; ++j) {
                int wi = ro - j;
                if (wi >= 0 && wi < 63) acc[j] += W[wi] * v;
            }
        }
        #pragma unroll
        for (int j = 0; j < 16; ++j) vt[j * 580 + c] = acc[j];
    }
    __syncthreads();

    float m = -INFINITY;
    int row = t & 15;
    int chunk0 = t >> 4;
    float* dstrow = blur + (size_t)plane * PLANE + (size_t)(y0 + row) * WW;
    const float* vrow = vt + row * 580;
    #pragma unroll
    for (int pass = 0; pass < 2; ++pass) {
        int x0 = (chunk0 + (pass << 4)) << 4;
        float acc[16];
        #pragma unroll
        for (int j = 0; j < 16; ++j) acc[j] = 0.0f;
        const float4* v4 = (const float4*)(vrow + x0);
        #pragma unroll
        for (int mi = 0; mi < 20; ++mi) {
            float4 vv = v4[mi];
            #pragma unroll
            for (int e = 0; e < 4; ++e) {
                float xv = (e == 0) ? vv.x : (e == 1) ? vv.y : (e == 2) ? vv.z : vv.w;
                int k = (mi << 2) + e;
                #pragma unroll
                for (int j = 0; j < 16; ++j) {
                    int wi = k - j;
                    if (wi >= 0 && wi < 63) acc[j] += W[wi] * xv;
                }
            }
        }
        #pragma unroll
        for (int j = 0; j < 16; ++j) m = fmaxf(m, acc[j]);
        float4* dst4 = (float4*)(dstrow + x0);
        #pragma unroll
        for (int q = 0; q < 4; ++q)
            dst4[q] = make_float4(acc[4 * q], acc[4 * q + 1], acc[4 * q + 2], acc[4 * q + 3]);
    }

    for (int off = 32; off; off >>= 1) m = fmaxf(m, __shfl_down(m, off, 64));
    if ((t & 63) == 0) smax[t >> 6] = m;
    __syncthreads();
    if (t == 0)
        partials[blk] = fmaxf(fmaxf(smax[0], smax[1]), fmaxf(smax[2], smax[3]));
}

__global__ __launch_bounds__(256) void reduce_max_kernel(const float* __restrict__ partials,
                                                         float* __restrict__ maxv) {
    int f = blockIdx.x;
    int t = threadIdx.x;
    float m = partials[f * 256 + t];
    __shared__ float smax[4];
    for (int off = 32; off; off >>= 1) m = fmaxf(m, __shfl_down(m, off, 64));
    if ((t & 63) == 0) smax[t >> 6] = m;
    __syncthreads();
    if (t == 0)
        maxv[f] = fmaxf(fmaxf(smax[0], smax[1]), fmaxf(smax[2], smax[3]));
}

// 64x64-output tile per block, 512 threads. Fixed 129x132 input window staged
// in LDS per channel with unrolled float4 loads; issue-early prefetch of the
// next channel's window; uniform fallback to direct gather if displacement
// overshoots the +-32 halo (possible when |min(blur)| > max(blur)).
__global__ __launch_bounds__(512, 4) void warp_tiled_kernel(const float* __restrict__ xin,
                                                            const float* __restrict__ blur,
                                                            const float* __restrict__ maxv,
                                                            float* __restrict__ warped,
                                                            float2* __restrict__ gridout) {
    __shared__ __align__(16) float stage[LDS_N + 4];
    __shared__ float rminx[8], rmaxx[8], rminy[8], rmaxy[8];
    __shared__ int sok;

    int t = threadIdx.x;
    int bid = blockIdx.x;                 // 512 blocks: all co-resident
    int b = bid >> 6;
    int tile = bid & 63;
    int ty0 = (tile >> 3) << 6;
    int tx0 = (tile & 7) << 6;
    int wxs = min(max(tx0 - 32, 0), WW - WIN_C);   // mult of 4 (<=380)
    int wys = min(max(ty0 - 32, 0), HH - WIN_R);   // <=383

    float sx = SIGMA_F / maxv[0];
    float sy = SIGMA_F / maxv[1];

    int col = t & 63, row0 = t >> 6;      // 8 row-phases per thread

    float wx[8], wy[8];
    int o00[8], o10[8];
    float mnx = 1e30f, mxx = -1e30f, mny = 1e30f, mxy = -1e30f;

    #pragma unroll
    for (int k = 0; k < 8; ++k) {
        int gy = ty0 + row0 + 8 * k;
        int gx = tx0 + col;
        float dxv = blur[(size_t)b * PLANE + gy * WW + gx] * sx;
        float dyv = blur[(size_t)(BB + b) * PLANE + gy * WW + gx] * sy;
        float gnx = 2.0f * ((float)gx + dxv) / 511.0f - 1.0f;
        float gny = 2.0f * ((float)gy + dyv) / 511.0f - 1.0f;
        gridout[((size_t)b * HH + gy) * WW + gx] = make_float2(gnx, gny);
        float ix = (gnx + 1.0f) * 0.5f * 511.0f;
        float iy = (gny + 1.0f) * 0.5f * 511.0f;
        ix = fminf(fmaxf(ix, 0.0f), 511.0f);
        iy = fminf(fmaxf(iy, 0.0f), 511.0f);
        float fx = floorf(ix), fy = floorf(iy);
        wx[k] = ix - fx;  wy[k] = iy - fy;
        int x0 = (int)fx, y0 = (int)fy;
        o00[k] = (y0 - wys) * WIN_C + (x0 - wxs);
        o10[k] = o00[k] + ((y0 < HH - 1) ? WIN_C : 0);
        mnx = fminf(mnx, ix); mxx = fmaxf(mxx, ix);
        mny = fminf(mny, iy); mxy = fmaxf(mxy, iy);
    }
    int obase = (ty0 + row0) * WW + tx0 + col;

    for (int off = 32; off; off >>= 1) {
        mnx = fminf(mnx, __shfl_xor(mnx, off, 64));
        mxx = fmaxf(mxx, __shfl_xor(mxx, off, 64));
        mny = fminf(mny, __shfl_xor(mny, off, 64));
        mxy = fmaxf(mxy, __shfl_xor(mxy, off, 64));
    }
    if ((t & 63) == 0) {
        int wv = t >> 6;
        rminx[wv] = mnx; rmaxx[wv] = mxx; rminy[wv] = mny; rmaxy[wv] = mxy;
    }
    if (t < 4) stage[LDS_N + t] = 0.0f;   // NaN-proof pad for x0==511 edge reads
    __syncthreads();
    if (t == 0) {
        float a = rminx[0], bx = rmaxx[0], c = rminy[0], d = rmaxy[0];
        #pragma unroll
        for (int i = 1; i < 8; ++i) {
            a = fminf(a, rminx[i]); bx = fmaxf(bx, rmaxx[i]);
            c = fminf(c, rminy[i]); d = fmaxf(d, rmaxy[i]);
        }
        int X0 = (int)floorf(a), X1r = min((int)floorf(bx) + 1, WW - 1);
        int Y0 = (int)floorf(c), Y1r = min((int)floorf(d) + 1, HH - 1);
        sok = (X0 >= wxs) && (X1r <= wxs + WIN_C - 1) &&
              (Y0 >= wys) && (Y1r <= wys + WIN_R - 1);
    }
    __syncthreads();
    int ok = sok;

    const float* xb = xin + (size_t)b * CC * PLANE + (size_t)wys * WW + wxs;
    float* wb = warped + (size_t)b * CC * PLANE;

    if (ok) {
        // precompute staging offsets once (channel-invariant)
        int ldsoff[9], srcoff[9];
        #pragma unroll
        for (int k = 0; k < 9; ++k) {
            int fi = min(t + 512 * k, NF4 - 1);
            int r = fi / 33;              // const-divisor magic mul
            int c4 = fi - r * 33;
            ldsoff[k] = r * WIN_C + c4 * 4;
            srcoff[k] = r * WW + c4 * 4;
        }

        float4 rb[9];
        {
            const float* s0 = xb;         // channel 0
            #pragma unroll
            for (int k = 0; k < 9; ++k)
                rb[k] = *(const float4*)(s0 + srcoff[k]);
        }

        for (int c = 0; c < CC; ++c) {
            if (c > 0) {
                float* dstc = wb + (size_t)(c - 1) * PLANE;
                #pragma unroll
                for (int k = 0; k < 8; ++k) {
                    float v00 = stage[o00[k]], v01 = stage[o00[k] + 1];
                    float v10 = stage[o10[k]], v11 = stage[o10[k] + 1];
                    float vt = v00 + wx[k] * (v01 - v00);
                    float vb = v10 + wx[k] * (v11 - v10);
                    dstc[obase + k * 8 * WW] = vt + wy[k] * (vb - vt);
                }
            }
            __syncthreads();              // sampling of c-1 done
            #pragma unroll
            for (int k = 0; k < 9; ++k)
                *(float4*)&stage[ldsoff[k]] = rb[k];
            __syncthreads();              // window c staged
            if (c < CC - 1) {
                const float* sn = xb + (size_t)(c + 1) * PLANE;
                #pragma unroll
                for (int k = 0; k < 9; ++k)
                    rb[k] = *(const float4*)(sn + srcoff[k]);   // in flight during sample(c)
            }
        }
        {
            float* dstc = wb + (size_t)(CC - 1) * PLANE;
            #pragma unroll
            for (int k = 0; k < 8; ++k) {
                float v00 = stage[o00[k]], v01 = stage[o00[k] + 1];
                float v10 = stage[o10[k]], v11 = stage[o10[k] + 1];
                float vt = v00 + wx[k] * (v01 - v00);
                float vb = v10 + wx[k] * (v11 - v10);
                dstc[obase + k * 8 * WW] = vt + wy[k] * (vb - vt);
            }
        }
    } else {
        // rare fallback: recompute indices, direct global gather
        const float* xbf = xin + (size_t)b * CC * PLANE;
        #pragma unroll
        for (int k = 0; k < 8; ++k) {
            int gy = ty0 + row0 + 8 * k;
            int gx = tx0 + col;
            float dxv = blur[(size_t)b * PLANE + gy * WW + gx] * sx;
            float dyv = blur[(size_t)(BB + b) * PLANE + gy * WW + gx] * sy;
            float ix = ((float)gx + dxv);
            float iy = ((float)gy + dyv);
            ix = fminf(fmaxf(2.0f * ix / 511.0f - 1.0f, -1.0f), 1.0f);
            iy = fminf(fmaxf(2.0f * iy / 511.0f - 1.0f, -1.0f), 1.0f);
            ix = (ix + 1.0f) * 0.5f * 511.0f;
            iy = (iy + 1.0f) * 0.5f * 511.0f;
            ix = fminf(fmaxf(ix, 0.0f), 511.0f);
            iy = fminf(fmaxf(iy, 0.0f), 511.0f);
            float fx = floorf(ix), fy = floorf(iy);
            float wxk = ix - fx, wyk = iy - fy;
            int x0 = (int)fx, y0 = (int)fy;
            int x1 = min(x0 + 1, WW - 1), y1 = min(y0 + 1, HH - 1);
            int p00 = y0 * WW + x0, p01 = y0 * WW + x1;
            int p10 = y1 * WW + x0, p11 = y1 * WW + x1;
            for (int c = 0; c < CC; ++c) {
                const float* src = xbf + (size_t)c * PLANE;
                float v00 = src[p00], v01 = src[p01], v10 = src[p10], v11 = src[p11];
                float vt = v00 + wxk * (v01 - v00);
                float vb = v10 + wxk * (v11 - v10);
                wb[(size_t)c * PLANE + obase + k * 8 * WW] = vt + wyk * (vb - vt);
            }
        }
    }
}

extern "C" void kernel_launch(void* const* d_in, const int* in_sizes, int n_in,
                              void* d_out, int out_size, void* d_ws, size_t ws_size,
                              hipStream_t stream) {
    const float* x   = (const float*)d_in[0];
    const float* dxn = (const float*)d_in[1];
    const float* dyn = (const float*)d_in[2];

    float* ws = (float*)d_ws;
    float* blur     = ws;                       // 16*512*512 floats
    float* partials = ws + 4194304;             // 512 floats
    float* maxv     = ws + 4194304 + 512;       // 2 floats

    float* warped   = (float*)d_out;
    float2* gridout = (float2*)((float*)d_out + (size_t)BB * CC * PLANE);

    blur_fused_kernel<<<16 * 32, 256, 0, stream>>>(dxn, dyn, blur, partials);
    reduce_max_kernel<<<2, 256, 0, stream>>>(partials, maxv);
    warp_tiled_kernel<<<BB * 64, 512, 0, stream>>>(x, blur, maxv, warped, gridout);
}

// Round 5
// 306.165 us; speedup vs baseline: 2.1135x; 2.1135x over previous
//
#include <hip/hip_runtime.h>
#include <math.h>

#define SIGMA_F 32.0f
#define BB 8
#define CC 31
#define HH 512
#define WW 512
#define PLANE (HH * WW)

// ---- compile-time Gaussian weights: W[i] = exp(-i^2 / 2048) ----
constexpr double cexp_neg(double t) {
    double u = -t / 16.0;
    double s = 1.0, term = 1.0;
    for (int k = 1; k < 14; ++k) { term *= u / (double)k; s += term; }
    s = s * s; s = s * s; s = s * s; s = s * s;
    return s;
}
constexpr float gwf(int i) { return (float)cexp_neg((double)(i * i) / 2048.0); }

__device__ constexpr float W[64] = {
    gwf(0),  gwf(1),  gwf(2),  gwf(3),  gwf(4),  gwf(5),  gwf(6),  gwf(7),
    gwf(8),  gwf(9),  gwf(10), gwf(11), gwf(12), gwf(13), gwf(14), gwf(15),
    gwf(16), gwf(17), gwf(18), gwf(19), gwf(20), gwf(21), gwf(22), gwf(23),
    gwf(24), gwf(25), gwf(26), gwf(27), gwf(28), gwf(29), gwf(30), gwf(31),
    gwf(32), gwf(33), gwf(34), gwf(35), gwf(36), gwf(37), gwf(38), gwf(39),
    gwf(40), gwf(41), gwf(42), gwf(43), gwf(44), gwf(45), gwf(46), gwf(47),
    gwf(48), gwf(49), gwf(50), gwf(51), gwf(52), gwf(53), gwf(54), gwf(55),
    gwf(56), gwf(57), gwf(58), gwf(59), gwf(60), gwf(61), gwf(62), 0.0f
};

__global__ __launch_bounds__(256, 2) void blur_fused_kernel(const float* __restrict__ dxn,
                                                            const float* __restrict__ dyn,
                                                            float* __restrict__ blur,
                                                            float* __restrict__ partials) {
    __shared__ __align__(16) float vt[16 * 580];
    __shared__ float smax[4];
    int t = threadIdx.x;
    int blk = blockIdx.x;
    int plane = blk >> 5;
    int band = blk & 31;
    int y0 = band << 4;
    const float* src = (plane < BB) ? dxn + (size_t)plane * PLANE
                                    : dyn + (size_t)(plane - BB) * PLANE;

    for (int c = t; c < 574; c += 256) {
        int L = c - 31;
        int scol = (L < 0) ? -L : ((L > HH - 1) ? 2 * HH - 2 - L : L);
        float acc[16];
        #pragma unroll
        for (int j = 0; j < 16; ++j) acc[j] = 0.0f;
        #pragma unroll
        for (int ro = 0; ro < 78; ++ro) {
            int rr = y0 - 31 + ro;
            int r = (rr < 0) ? -rr : ((rr > HH - 1) ? 2 * HH - 2 - rr : rr);
            float v = src[r * WW + scol];
            #pragma unroll
            for (int j = 0; j < 16; ++j) {
                int wi = ro - j;
                if (wi >= 0 && wi < 63) acc[j] += W[wi] * v;
            }
        }
        #pragma unroll
        for (int j = 0; j < 16; ++j) vt[j * 580 + c] = acc[j];
    }
    __syncthreads();

    float m = -INFINITY;
    int row = t & 15;
    int chunk0 = t >> 4;
    float* dstrow = blur + (size_t)plane * PLANE + (size_t)(y0 + row) * WW;
    const float* vrow = vt + row * 580;
    #pragma unroll
    for (int pass = 0; pass < 2; ++pass) {
        int x0 = (chunk0 + (pass << 4)) << 4;
        float acc[16];
        #pragma unroll
        for (int j = 0; j < 16; ++j) acc[j] = 0.0f;
        const float4* v4 = (const float4*)(vrow + x0);
        #pragma unroll
        for (int mi = 0; mi < 20; ++mi) {
            float4 vv = v4[mi];
            #pragma unroll
            for (int e = 0; e < 4; ++e) {
                float xv = (e == 0) ? vv.x : (e == 1) ? vv.y : (e == 2) ? vv.z : vv.w;
                int k = (mi << 2) + e;
                #pragma unroll
                for (int j = 0; j < 16; ++j) {
                    int wi = k - j;
                    if (wi >= 0 && wi < 63) acc[j] += W[wi] * xv;
                }
            }
        }
        #pragma unroll
        for (int j = 0; j < 16; ++j) m = fmaxf(m, acc[j]);
        float4* dst4 = (float4*)(dstrow + x0);
        #pragma unroll
        for (int q = 0; q < 4; ++q)
            dst4[q] = make_float4(acc[4 * q], acc[4 * q + 1], acc[4 * q + 2], acc[4 * q + 3]);
    }

    for (int off = 32; off; off >>= 1) m = fmaxf(m, __shfl_down(m, off, 64));
    if ((t & 63) == 0) smax[t >> 6] = m;
    __syncthreads();
    if (t == 0)
        partials[blk] = fmaxf(fmaxf(smax[0], smax[1]), fmaxf(smax[2], smax[3]));
}

__global__ __launch_bounds__(256) void reduce_max_kernel(const float* __restrict__ partials,
                                                         float* __restrict__ maxv) {
    int f = blockIdx.x;
    int t = threadIdx.x;
    float m = partials[f * 256 + t];
    __shared__ float smax[4];
    for (int off = 32; off; off >>= 1) m = fmaxf(m, __shfl_down(m, off, 64));
    if ((t & 63) == 0) smax[t >> 6] = m;
    __syncthreads();
    if (t == 0)
        maxv[f] = fmaxf(fmaxf(smax[0], smax[1]), fmaxf(smax[2], smax[3]));
}

// 8-byte tap-pair load: (v00,v01) and (v10,v11) each as one dwordx2.
// align(4) lets LLVM emit global_load_dwordx2 at dword (not 8B) alignment,
// which gfx950 supports.
struct __attribute__((aligned(4))) F2 { float a, b; };

// Warp (grid-sample) kernel, channel-grouped + XCD-swizzled (round-2 structure).
// wid = (cg*8 + b)*512 + h; XCD k owns a contiguous 2048-wid chunk.
__global__ __launch_bounds__(256) void warp_kernel(const float* __restrict__ xin,
                                                   const float* __restrict__ blur,
                                                   const float* __restrict__ maxv,
                                                   float* __restrict__ warped,
                                                   float2* __restrict__ gridout) {
    int bid = blockIdx.x;
    int wid = (bid & 7) * 2048 + (bid >> 3);
    int h = wid & 511;
    int bcg = wid >> 9;            // 0..31
    int cg = bcg >> 3;             // 0..3
    int b = bcg & 7;
    int c0 = cg * 8;
    int nc = (cg < 3) ? 8 : 7;
    int t = threadIdx.x;

    float sx = SIGMA_F / maxv[0];
    float sy = SIGMA_F / maxv[1];

    const float* bdx = blur + (size_t)b * PLANE + (size_t)h * WW;
    const float* bdy = blur + (size_t)(BB + b) * PLANE + (size_t)h * WW;
    const float* xg = xin + (size_t)b * CC * PLANE + (size_t)c0 * PLANE;
    float* wout_base = warped + (size_t)b * CC * PLANE + (size_t)c0 * PLANE + (size_t)h * WW;

    #pragma unroll
    for (int ww = 0; ww < 2; ++ww) {
        int w = t + ww * 256;
        float dx = bdx[w] * sx;
        float dy = bdy[w] * sy;
        float gnx = 2.0f * ((float)w + dx) / 511.0f - 1.0f;
        float gny = 2.0f * ((float)h + dy) / 511.0f - 1.0f;

        if (cg == 0)
            gridout[((size_t)b * HH + h) * WW + w] = make_float2(gnx, gny);

        float ix = (gnx + 1.0f) * 0.5f * 511.0f;
        float iy = (gny + 1.0f) * 0.5f * 511.0f;
        ix = fminf(fmaxf(ix, 0.0f), 511.0f);
        iy = fminf(fmaxf(iy, 0.0f), 511.0f);
        float x0f = floorf(ix), y0f = floorf(iy);
        float wx = ix - x0f, wy = iy - y0f;
        int x0 = (int)x0f, y0 = (int)y0f;
        // border-replication via clamp trick: keeps the 8B pair in-bounds
        if (x0 > WW - 2) { x0 = WW - 2; wx = 1.0f; }
        if (y0 > HH - 2) { y0 = HH - 2; wy = 1.0f; }
        int o00 = y0 * WW + x0;        // pair (v00,v01)
        int o10 = o00 + WW;            // pair (v10,v11)

        float* wout = wout_base + w;
        #pragma unroll
        for (int c = 0; c < 8; ++c) {
            if (c < nc) {
                const float* xc = xg + (size_t)c * PLANE;
                F2 p0 = *(const F2*)(xc + o00);
                F2 p1 = *(const F2*)(xc + o10);
                float top = p0.a + wx * (p0.b - p0.a);
                float bot = p1.a + wx * (p1.b - p1.a);
                wout[(size_t)c * PLANE] = top + wy * (bot - top);
            }
        }
    }
}

extern "C" void kernel_launch(void* const* d_in, const int* in_sizes, int n_in,
                              void* d_out, int out_size, void* d_ws, size_t ws_size,
                              hipStream_t stream) {
    const float* x   = (const float*)d_in[0];
    const float* dxn = (const float*)d_in[1];
    const float* dyn = (const float*)d_in[2];

    float* ws = (float*)d_ws;
    float* blur     = ws;                       // 16*512*512 floats
    float* partials = ws + 4194304;             // 512 floats
    float* maxv     = ws + 4194304 + 512;       // 2 floats

    float* warped   = (float*)d_out;
    float2* gridout = (float2*)((float*)d_out + (size_t)BB * CC * PLANE);

    blur_fused_kernel<<<16 * 32, 256, 0, stream>>>(dxn, dyn, blur, partials);
    reduce_max_kernel<<<2, 256, 0, stream>>>(partials, maxv);
    warp_kernel<<<BB * 4 * HH, 256, 0, stream>>>(x, blur, maxv, warped, gridout);
}

// Round 6
// 162.271 us; speedup vs baseline: 3.9876x; 1.8868x over previous
//
#include <hip/hip_runtime.h>
#include <math.h>

#define SIGMA_F 32.0f
#define BB 8
#define CC 31
#define HH 512
#define WW 512
#define PLANE (HH * WW)

// ---- compile-time Gaussian weights: W[i] = exp(-i^2 / 2048) ----
constexpr double cexp_neg(double t) {
    double u = -t / 16.0;
    double s = 1.0, term = 1.0;
    for (int k = 1; k < 14; ++k) { term *= u / (double)k; s += term; }
    s = s * s; s = s * s; s = s * s; s = s * s;
    return s;
}
constexpr float gwf(int i) { return (float)cexp_neg((double)(i * i) / 2048.0); }

__device__ constexpr float W[64] = {
    gwf(0),  gwf(1),  gwf(2),  gwf(3),  gwf(4),  gwf(5),  gwf(6),  gwf(7),
    gwf(8),  gwf(9),  gwf(10), gwf(11), gwf(12), gwf(13), gwf(14), gwf(15),
    gwf(16), gwf(17), gwf(18), gwf(19), gwf(20), gwf(21), gwf(22), gwf(23),
    gwf(24), gwf(25), gwf(26), gwf(27), gwf(28), gwf(29), gwf(30), gwf(31),
    gwf(32), gwf(33), gwf(34), gwf(35), gwf(36), gwf(37), gwf(38), gwf(39),
    gwf(40), gwf(41), gwf(42), gwf(43), gwf(44), gwf(45), gwf(46), gwf(47),
    gwf(48), gwf(49), gwf(50), gwf(51), gwf(52), gwf(53), gwf(54), gwf(55),
    gwf(56), gwf(57), gwf(58), gwf(59), gwf(60), gwf(61), gwf(62), 0.0f
};

__global__ __launch_bounds__(256, 2) void blur_fused_kernel(const float* __restrict__ dxn,
                                                            const float* __restrict__ dyn,
                                                            float* __restrict__ blur,
                                                            float* __restrict__ partials) {
    __shared__ __align__(16) float vt[16 * 580];
    __shared__ float smax[4];
    int t = threadIdx.x;
    int blk = blockIdx.x;
    int plane = blk >> 5;
    int band = blk & 31;
    int y0 = band << 4;
    const float* src = (plane < BB) ? dxn + (size_t)plane * PLANE
                                    : dyn + (size_t)(plane - BB) * PLANE;

    for (int c = t; c < 574; c += 256) {
        int L = c - 31;
        int scol = (L < 0) ? -L : ((L > HH - 1) ? 2 * HH - 2 - L : L);
        float acc[16];
        #pragma unroll
        for (int j = 0; j < 16; ++j) acc[j] = 0.0f;
        #pragma unroll
        for (int ro = 0; ro < 78; ++ro) {
            int rr = y0 - 31 + ro;
            int r = (rr < 0) ? -rr : ((rr > HH - 1) ? 2 * HH - 2 - rr : rr);
            float v = src[r * WW + scol];
            #pragma unroll
            for (int j = 0; j < 16; ++j) {
                int wi = ro - j;
                if (wi >= 0 && wi < 63) acc[j] += W[wi] * v;
            }
        }
        #pragma unroll
        for (int j = 0; j < 16; ++j) vt[j * 580 + c] = acc[j];
    }
    __syncthreads();

    float m = -INFINITY;
    int row = t & 15;
    int chunk0 = t >> 4;
    float* dstrow = blur + (size_t)plane * PLANE + (size_t)(y0 + row) * WW;
    const float* vrow = vt + row * 580;
    #pragma unroll
    for (int pass = 0; pass < 2; ++pass) {
        int x0 = (chunk0 + (pass << 4)) << 4;
        float acc[16];
        #pragma unroll
        for (int j = 0; j < 16; ++j) acc[j] = 0.0f;
        const float4* v4 = (const float4*)(vrow + x0);
        #pragma unroll
        for (int mi = 0; mi < 20; ++mi) {
            float4 vv = v4[mi];
            #pragma unroll
            for (int e = 0; e < 4; ++e) {
                float xv = (e == 0) ? vv.x : (e == 1) ? vv.y : (e == 2) ? vv.z : vv.w;
                int k = (mi << 2) + e;
                #pragma unroll
                for (int j = 0; j < 16; ++j) {
                    int wi = k - j;
                    if (wi >= 0 && wi < 63) acc[j] += W[wi] * xv;
                }
            }
        }
        #pragma unroll
        for (int j = 0; j < 16; ++j) m = fmaxf(m, acc[j]);
        float4* dst4 = (float4*)(dstrow + x0);
        #pragma unroll
        for (int q = 0; q < 4; ++q)
            dst4[q] = make_float4(acc[4 * q], acc[4 * q + 1], acc[4 * q + 2], acc[4 * q + 3]);
    }

    for (int off = 32; off; off >>= 1) m = fmaxf(m, __shfl_down(m, off, 64));
    if ((t & 63) == 0) smax[t >> 6] = m;
    __syncthreads();
    if (t == 0)
        partials[blk] = fmaxf(fmaxf(smax[0], smax[1]), fmaxf(smax[2], smax[3]));
}

__global__ __launch_bounds__(256) void reduce_max_kernel(const float* __restrict__ partials,
                                                         float* __restrict__ maxv) {
    int f = blockIdx.x;
    int t = threadIdx.x;
    float m = partials[f * 256 + t];
    __shared__ float smax[4];
    for (int off = 32; off; off >>= 1) m = fmaxf(m, __shfl_down(m, off, 64));
    if ((t & 63) == 0) smax[t >> 6] = m;
    __syncthreads();
    if (t == 0)
        maxv[f] = fmaxf(fmaxf(smax[0], smax[1]), fmaxf(smax[2], smax[3]));
}

// async global->LDS, 16B per lane; LDS dest = wave-uniform base + lane*16
__device__ __forceinline__ void gload_lds16(const float* g, float* l) {
    __builtin_amdgcn_global_load_lds(
        (const __attribute__((address_space(1))) void*)g,
        (__attribute__((address_space(3))) void*)l,
        16, 0, 0);
}

// 64x64 tile per block, 256 threads. 128x128-float window staged per channel
// via global_load_lds (no VGPR round trip -> no spill). Taps become LDS reads
// (bank = (x0-wxs)%32, consecutive across lanes -> ~conflict-free).
__global__ __launch_bounds__(256) void warp_tiled_kernel(const float* __restrict__ xin,
                                                         const float* __restrict__ blur,
                                                         const float* __restrict__ maxv,
                                                         float* __restrict__ warped,
                                                         float2* __restrict__ gridout) {
    __shared__ __align__(16) float stage[128 * 128];
    __shared__ int rx0[4], rx1[4], ry0[4], ry1[4];
    __shared__ int sokv;

    int t = threadIdx.x;
    int bid = blockIdx.x;
    int b = bid & 7;               // XCD j owns batch j
    int tile = bid >> 3;           // row-major tiles within the batch
    int ty0 = (tile >> 3) << 6;
    int tx0 = (tile & 7) << 6;
    int wxs = min(max(tx0 - 32, 0), WW - 128);   // 128B-aligned
    int wys = min(max(ty0 - 32, 0), HH - 128);

    float sx = SIGMA_F / maxv[0];
    float sy = SIGMA_F / maxv[1];
    int col = t & 63, row0 = t >> 6;

    float wxa[16], wya[16];
    int oa[16];
    int x0mn = 1 << 30, x0mx = -1, y0mn = 1 << 30, y0mx = -1;

    const float* bdx = blur + (size_t)b * PLANE;
    const float* bdy = blur + (size_t)(BB + b) * PLANE;

    #pragma unroll
    for (int k = 0; k < 16; ++k) {
        int gy = ty0 + row0 + 4 * k;
        int gx = tx0 + col;
        float dxv = bdx[gy * WW + gx] * sx;
        float dyv = bdy[gy * WW + gx] * sy;
        float gnx = 2.0f * ((float)gx + dxv) / 511.0f - 1.0f;
        float gny = 2.0f * ((float)gy + dyv) / 511.0f - 1.0f;
        gridout[((size_t)b * HH + gy) * WW + gx] = make_float2(gnx, gny);
        float ix = (gnx + 1.0f) * 0.5f * 511.0f;
        float iy = (gny + 1.0f) * 0.5f * 511.0f;
        ix = fminf(fmaxf(ix, 0.0f), 511.0f);
        iy = fminf(fmaxf(iy, 0.0f), 511.0f);
        float fx = floorf(ix), fy = floorf(iy);
        float wx = ix - fx, wy = iy - fy;
        int x0 = (int)fx, y0 = (int)fy;
        if (x0 > WW - 2) { x0 = WW - 2; wx = 1.0f; }   // border clamp trick
        if (y0 > HH - 2) { y0 = HH - 2; wy = 1.0f; }
        wxa[k] = wx; wya[k] = wy;
        oa[k] = (y0 - wys) * 128 + (x0 - wxs);
        x0mn = min(x0mn, x0); x0mx = max(x0mx, x0);
        y0mn = min(y0mn, y0); y0mx = max(y0mx, y0);
    }

    for (int off = 32; off; off >>= 1) {
        x0mn = min(x0mn, __shfl_xor(x0mn, off, 64));
        x0mx = max(x0mx, __shfl_xor(x0mx, off, 64));
        y0mn = min(y0mn, __shfl_xor(y0mn, off, 64));
        y0mx = max(y0mx, __shfl_xor(y0mx, off, 64));
    }
    if ((t & 63) == 0) {
        int wv = t >> 6;
        rx0[wv] = x0mn; rx1[wv] = x0mx; ry0[wv] = y0mn; ry1[wv] = y0mx;
    }
    __syncthreads();
    if (t == 0) {
        int a = rx0[0], bx = rx1[0], c = ry0[0], d = ry1[0];
        #pragma unroll
        for (int i = 1; i < 4; ++i) {
            a = min(a, rx0[i]); bx = max(bx, rx1[i]);
            c = min(c, ry0[i]); d = max(d, ry1[i]);
        }
        sokv = (a >= wxs) && (bx <= wxs + 126) && (c >= wys) && (d <= wys + 126);
    }
    __syncthreads();
    int ok = sokv;

    const float* xb = xin + (size_t)b * CC * PLANE;
    float* wb = warped + (size_t)b * CC * PLANE;
    int obase = (ty0 + row0) * WW + tx0 + col;

    if (ok) {
        int wave = t >> 6, lane = t & 63;
        int srow = 2 * wave + (lane >> 5);           // start row 0..7
        int scol4 = (lane & 31) * 4;
        const float* gbase = xb + (size_t)(wys + srow) * WW + wxs + scol4;
        float* lbase = stage + 2 * wave * 128;       // wave-uniform

        for (int c = 0; c < CC; ++c) {
            const float* g = gbase + (size_t)c * PLANE;
            #pragma unroll
            for (int i = 0; i < 16; ++i)
                gload_lds16(g + i * 8 * WW, lbase + i * 8 * 128);
            __syncthreads();                          // drains vmcnt: window ready
            float* dstc = wb + (size_t)c * PLANE;
            #pragma unroll
            for (int k = 0; k < 16; ++k) {
                float v00 = stage[oa[k]],       v01 = stage[oa[k] + 1];
                float v10 = stage[oa[k] + 128], v11 = stage[oa[k] + 129];
                float tp = v00 + wxa[k] * (v01 - v00);
                float bt = v10 + wxa[k] * (v11 - v10);
                dstc[obase + k * 4 * WW] = tp + wya[k] * (bt - tp);
            }
            __syncthreads();                          // reads done before overwrite
        }
    } else {
        // rare fallback: direct global gather (identical arithmetic)
        #pragma unroll
        for (int k = 0; k < 16; ++k) {
            int gy = ty0 + row0 + 4 * k;
            int gx = tx0 + col;
            float dxv = bdx[gy * WW + gx] * sx;
            float dyv = bdy[gy * WW + gx] * sy;
            float gnx = 2.0f * ((float)gx + dxv) / 511.0f - 1.0f;
            float gny = 2.0f * ((float)gy + dyv) / 511.0f - 1.0f;
            float ix = (gnx + 1.0f) * 0.5f * 511.0f;
            float iy = (gny + 1.0f) * 0.5f * 511.0f;
            ix = fminf(fmaxf(ix, 0.0f), 511.0f);
            iy = fminf(fmaxf(iy, 0.0f), 511.0f);
            float fx = floorf(ix), fy = floorf(iy);
            float wx = ix - fx, wy = iy - fy;
            int x0 = (int)fx, y0 = (int)fy;
            if (x0 > WW - 2) { x0 = WW - 2; wx = 1.0f; }
            if (y0 > HH - 2) { y0 = HH - 2; wy = 1.0f; }
            int o00 = y0 * WW + x0;
            for (int c = 0; c < CC; ++c) {
                const float* src = xb + (size_t)c * PLANE;
                float v00 = src[o00], v01 = src[o00 + 1];
                float v10 = src[o00 + WW], v11 = src[o00 + WW + 1];
                float tp = v00 + wx * (v01 - v00);
                float bt = v10 + wx * (v11 - v10);
                wb[(size_t)c * PLANE + obase + k * 4 * WW] = tp + wy * (bt - tp);
            }
        }
    }
}

extern "C" void kernel_launch(void* const* d_in, const int* in_sizes, int n_in,
                              void* d_out, int out_size, void* d_ws, size_t ws_size,
                              hipStream_t stream) {
    const float* x   = (const float*)d_in[0];
    const float* dxn = (const float*)d_in[1];
    const float* dyn = (const float*)d_in[2];

    float* ws = (float*)d_ws;
    float* blur     = ws;                       // 16*512*512 floats
    float* partials = ws + 4194304;             // 512 floats
    float* maxv     = ws + 4194304 + 512;       // 2 floats

    float* warped   = (float*)d_out;
    float2* gridout = (float2*)((float*)d_out + (size_t)BB * CC * PLANE);

    blur_fused_kernel<<<16 * 32, 256, 0, stream>>>(dxn, dyn, blur, partials);
    reduce_max_kernel<<<2, 256, 0, stream>>>(partials, maxv);
    warp_tiled_kernel<<<BB * 64, 256, 0, stream>>>(x, blur, maxv, warped, gridout);
}